// Round 1
// baseline (358886.182 us; speedup 1.0000x reference)
//
#include <hip/hip_runtime.h>
#include <math.h>

// NeuralCDE on MI355X: sequential Tsit5 chain (2047*4 steps, 6 vf evals each).
// Weight-stationary across 32 persistent WGs (weights row-split in LDS),
// LLC flag-barriers (2 per vf eval), fully deterministic fp32.

#define T_SAVE 2048
#define NCTRL 8
#define HID 128
#define WID 512
#define IN_DIM 136            // HID + NCTRL
#define NSUB 4
#define NWG 32
#define NT 512
#define RW 16                 // WID / NWG rows per WG (L1, L2)
#define LC 16                 // WID / NWG local cols per WG (L3 column split)

// ---- Tsit5 tableau (fp32, same literals as reference) ----
__device__ const float d_C[6] = {0.0f, 0.161f, 0.327f, 0.9f, 0.9800255409045097f, 1.0f};
__device__ const float d_AT[5][5] = {
  {0.161f, 0.f, 0.f, 0.f, 0.f},
  {-0.008480655492356989f, 0.335480655492357f, 0.f, 0.f, 0.f},
  {2.8971530571054935f, -6.359448489975075f, 4.3622954328695815f, 0.f, 0.f},
  {5.325864828439257f, -11.748883564062828f, 7.4955393428898365f, -0.09249506636175525f, 0.f},
  {5.86145544294642f, -12.92096931784711f, 8.159367898576159f, -0.071584973281401f, -0.028269050394068383f}
};
__device__ const float d_BT[6] = {0.09646076681806523f, 0.01f, 0.4798896504144996f,
                                  1.379008574103742f, -3.290069515436081f, 2.324710524099774f};

__device__ __forceinline__ float softplus_f(float x) {
  // jax.nn.softplus = max(x,0) + log1p(exp(-|x|))
  return fmaxf(x, 0.0f) + log1pf(expf(-fabsf(x)));
}

// LLC-coherent data accesses (agent scope, relaxed): visibility does not
// depend on L2 writeback fences — every access hits the coherence point.
__device__ __forceinline__ void g_storef(float* p, float v) {
  __hip_atomic_store(p, v, __ATOMIC_RELAXED, __HIP_MEMORY_SCOPE_AGENT);
}
__device__ __forceinline__ float g_loadf(float* p) {
  return __hip_atomic_load(p, __ATOMIC_RELAXED, __HIP_MEMORY_SCOPE_AGENT);
}

// diffrax CubicInterpolation.evaluate: idx = clip(searchsorted(ts,t,'right')-1, 0, T-2)
__device__ __forceinline__ float ctrl_u(const float* __restrict__ ts,
                                        const float* __restrict__ ca, const float* __restrict__ cb,
                                        const float* __restrict__ cc, const float* __restrict__ cd,
                                        float t, int hint, int ch) {
  int idx = hint;
  while (idx + 1 <= T_SAVE - 1 && ts[idx + 1] <= t) ++idx;  // forward scan (t >= ts[hint])
  while (idx > 0 && ts[idx] > t) --idx;                     // safety
  if (idx > T_SAVE - 2) idx = T_SAVE - 2;
  float x = t - ts[idx];
  int o = idx * NCTRL + ch;
  return ca[o] + x * (cb[o] + x * (cc[o] + x * cd[o]));
}

// Epoch flag barrier: each WG owns one 128B slot. Release-store own epoch,
// 32 lanes poll the 32 slots in parallel with acquire loads. Guard + sticky
// dead-flag: on timeout we stop waiting but keep posting epochs, so a broken
// run terminates fast (wrong answer) instead of hanging the queue.
__device__ __forceinline__ void gbar(unsigned int* slots, unsigned int e, int* deadp) {
  __syncthreads();
  if (threadIdx.x == 0) {
    __hip_atomic_store(&slots[blockIdx.x * 32], e, __ATOMIC_RELEASE, __HIP_MEMORY_SCOPE_AGENT);
  }
  if (threadIdx.x < NWG && !(*deadp)) {
    unsigned int guard = 0;
    while (__hip_atomic_load(&slots[threadIdx.x * 32], __ATOMIC_ACQUIRE,
                             __HIP_MEMORY_SCOPE_AGENT) < e) {
      __builtin_amdgcn_s_sleep(1);
      if (++guard > (1u << 14)) { *deadp = 1; break; }
    }
  }
  __syncthreads();
}

extern "C" __global__ void cde_init(unsigned int* wsu) {
  int i = threadIdx.x;
  if (i < NWG * 32) wsu[i] = 0;
}

extern "C" __global__ void __launch_bounds__(NT, 1)
cde_main(const float* __restrict__ ts,
         const float* __restrict__ cd, const float* __restrict__ cc,
         const float* __restrict__ cb, const float* __restrict__ ca,
         const float* __restrict__ Wi0, const float* __restrict__ bi0,
         const float* __restrict__ Wi1, const float* __restrict__ bi1,
         const float* __restrict__ Wi2, const float* __restrict__ bi2,
         const float* __restrict__ Wf0, const float* __restrict__ bf0,
         const float* __restrict__ Wf1, const float* __restrict__ bf1,
         const float* __restrict__ Wf2, const float* __restrict__ bf2,
         const float* __restrict__ Wl,  const float* __restrict__ bl,
         float* __restrict__ out, float* __restrict__ wsf, unsigned int* __restrict__ wsu)
{
  const int g = blockIdx.x;
  const int tid = threadIdx.x;

  unsigned int* slots = wsu;            // [NWG*32] epoch slots (4 KB)
  float* h1buf = wsf + 1024;            // [512]
  float* h2buf = wsf + 1536;            // [512] (init MLP only)
  float* ybuf  = wsf + 2048;            // [128] (init MLP only)
  float* pkbuf = wsf + 2176;            // [NWG*128] partial-k slots

  __shared__ __align__(16) float w0s[RW * IN_DIM];   // Wf0 row slice
  __shared__ __align__(16) float w1s[RW * WID];      // Wf1 row slice
  __shared__ __align__(16) float w2s[LC * HID];      // Wf2 col slice, [lc][i] (conflict-free)
  __shared__ float bf0s[RW], bf1s[RW], bf2s[HID];
  __shared__ __align__(16) float xv[IN_DIM];
  __shared__ __align__(16) float h1s[WID];
  __shared__ float h2s[RW];
  __shared__ float ks[6][HID];
  __shared__ float ysh[HID];
  __shared__ float psum[4 * HID];
  __shared__ int s_dead;

  unsigned int ep = 0;
  const int r0 = g * RW;
  if (tid == 0) s_dead = 0;

  // ---- stage this WG's weight slices into LDS (once per launch) ----
  for (int i = tid; i < RW * IN_DIM; i += NT) {
    int r = i / IN_DIM, c = i - r * IN_DIM;
    w0s[i] = Wf0[(r0 + r) * IN_DIM + c];
  }
  for (int i = tid; i < RW * WID; i += NT) {
    int r = i >> 9, c = i & (WID - 1);
    w1s[i] = Wf1[(r0 + r) * WID + c];
  }
  for (int i = tid; i < LC * HID; i += NT) {
    int lc = i >> 7, row = i & (HID - 1);
    w2s[i] = Wf2[row * WID + (g * LC + lc)];
  }
  if (tid < RW) { bf0s[tid] = bf0[r0 + tid]; bf1s[tid] = bf1[r0 + tid]; }
  if (tid < HID) bf2s[tid] = bf2[tid];

  // ---- init MLP: y0 = (Wi2 . relu(Wi1 . relu(Wi0 . u0 + bi0) + bi1) + bi2) ----
  if (tid < NCTRL) xv[HID + tid] = ctrl_u(ts, ca, cb, cc, cd, ts[0], 0, tid);
  __syncthreads();
  if (tid < RW) {
    float acc = bi0[r0 + tid];
    for (int e = 0; e < NCTRL; ++e) acc += Wi0[(r0 + tid) * NCTRL + e] * xv[HID + e];
    g_storef(&h1buf[r0 + tid], fmaxf(acc, 0.f));
  }
  ++ep; gbar(slots, ep, &s_dead);
  h1s[tid] = g_loadf(&h1buf[tid]);
  __syncthreads();
  {
    int w = tid >> 6, l = tid & 63;
    int ra = r0 + w * 2;
    float acc0 = 0.f, acc1 = 0.f;
    for (int m = 0; m < 2; ++m) {
      int c0 = 4 * l + 256 * m;
      float4 xq = *(const float4*)&h1s[c0];
      float4 wa = *(const float4*)&Wi1[(size_t)ra * WID + c0];
      float4 wb = *(const float4*)&Wi1[(size_t)(ra + 1) * WID + c0];
      acc0 += wa.x*xq.x + wa.y*xq.y + wa.z*xq.z + wa.w*xq.w;
      acc1 += wb.x*xq.x + wb.y*xq.y + wb.z*xq.z + wb.w*xq.w;
    }
    for (int o = 32; o; o >>= 1) { acc0 += __shfl_xor(acc0, o); acc1 += __shfl_xor(acc1, o); }
    if (l == 0) {
      g_storef(&h2buf[ra],     fmaxf(acc0 + bi1[ra], 0.f));
      g_storef(&h2buf[ra + 1], fmaxf(acc1 + bi1[ra + 1], 0.f));
    }
  }
  ++ep; gbar(slots, ep, &s_dead);
  h1s[tid] = g_loadf(&h2buf[tid]);
  __syncthreads();
  if (tid < 256) {
    int r = tid >> 6, l = tid & 63;
    int row = g * 4 + r;
    float acc = 0.f;
    for (int e = l; e < WID; e += 64) acc += Wi2[(size_t)row * WID + e] * h1s[e];
    for (int o = 32; o; o >>= 1) acc += __shfl_xor(acc, o);
    if (l == 0) g_storef(&ybuf[row], acc + bi2[row]);
  }
  ++ep; gbar(slots, ep, &s_dead);
  if (tid < HID) ysh[tid] = g_loadf(&ybuf[tid]);
  __syncthreads();
  if (g == 0 && tid < 96) {                      // out[0] = Wl @ y0 + bl
    int c = tid >> 5, l = tid & 31;
    float acc = 0.f;
    for (int e = l; e < HID; e += 32) acc += Wl[c * HID + e] * ysh[e];
    for (int o = 16; o; o >>= 1) acc += __shfl_xor(acc, o);
    if (l == 0) out[c] = acc + bl[c];
  }

  // ---- main sequential time loop ----
  for (int iv = 0; iv < T_SAVE - 1; ++iv) {
    float t0 = ts[iv], t1 = ts[iv + 1];
    float h = (t1 - t0) * 0.25f;                 // (t1-t0)/NSUB, exact
    for (int j = 0; j < NSUB; ++j) {
      float tj = t0 + (float)j * h;
      for (int s = 0; s < 6; ++s) {
        // build x = [y_stage ; u(t_stage)]
        if (tid < HID) {
          float v = ysh[tid];
          if (s > 0) {
            float inner = 0.f;
            for (int m = 0; m < s; ++m) inner += d_AT[s - 1][m] * ks[m][tid];
            v += h * inner;
          }
          xv[tid] = v;
        } else if (tid < IN_DIM) {
          float tst = tj + d_C[s] * h;
          xv[tid] = ctrl_u(ts, ca, cb, cc, cd, tst, iv, tid - HID);
        }
        __syncthreads();
        // Phase A: h1 slice = softplus(Wf0_slice @ x + b). 16 rows x 32 lanes.
        {
          int r = tid >> 5, c = tid & 31;
          float acc = 0.f;
          for (int e = c; e < IN_DIM; e += 32) acc += w0s[r * IN_DIM + e] * xv[e];
          for (int o = 16; o; o >>= 1) acc += __shfl_xor(acc, o);
          if (c == 0) g_storef(&h1buf[r0 + r], softplus_f(acc + bf0s[r]));
        }
        ++ep; gbar(slots, ep, &s_dead);
        // Phase B: gather h1, h2 slice (local), partial-k from Wf2 col slice.
        h1s[tid] = g_loadf(&h1buf[tid]);
        __syncthreads();
        {
          int w = tid >> 6, l = tid & 63;
          int ra = w * 2;
          float acc0 = 0.f, acc1 = 0.f;
          #pragma unroll
          for (int m = 0; m < 2; ++m) {
            int c0 = 4 * l + 256 * m;
            float4 xq = *(const float4*)&h1s[c0];
            float4 wa = *(const float4*)&w1s[ra * WID + c0];
            float4 wb = *(const float4*)&w1s[(ra + 1) * WID + c0];
            acc0 += wa.x*xq.x + wa.y*xq.y + wa.z*xq.z + wa.w*xq.w;
            acc1 += wb.x*xq.x + wb.y*xq.y + wb.z*xq.z + wb.w*xq.w;
          }
          for (int o = 32; o; o >>= 1) { acc0 += __shfl_xor(acc0, o); acc1 += __shfl_xor(acc1, o); }
          if (l == 0) {
            h2s[ra]     = softplus_f(acc0 + bf1s[ra]);
            h2s[ra + 1] = softplus_f(acc1 + bf1s[ra + 1]);
          }
        }
        __syncthreads();
        {
          int i = tid & (HID - 1), q = tid >> 7;
          float acc = 0.f;
          #pragma unroll
          for (int n = 0; n < 4; ++n) {
            int lc = q * 4 + n;
            acc += w2s[lc * HID + i] * h2s[lc];
          }
          psum[q * HID + i] = acc;
        }
        __syncthreads();
        if (tid < HID) {
          float tot = psum[tid] + psum[HID + tid] + psum[2 * HID + tid] + psum[3 * HID + tid];
          g_storef(&pkbuf[g * HID + tid], tot);
        }
        ++ep; gbar(slots, ep, &s_dead);
        // Phase C: deterministic sum of 32 partials -> k_s; redundant on all WGs.
        {
          int i = tid & (HID - 1), q = tid >> 7;
          float acc = 0.f;
          #pragma unroll
          for (int m = 0; m < 8; ++m) {
            int slot = q * 8 + m;
            acc += g_loadf(&pkbuf[slot * HID + i]);
          }
          psum[q * HID + i] = acc;
        }
        __syncthreads();
        if (tid < HID) {
          float tot = psum[tid] + psum[HID + tid] + psum[2 * HID + tid] + psum[3 * HID + tid];
          ks[s][tid] = tanhf(tot + bf2s[tid]);
        }
        __syncthreads();
      } // stages
      if (tid < HID) {
        float inner = 0.f;
        #pragma unroll
        for (int m = 0; m < 6; ++m) inner += d_BT[m] * ks[m][tid];
        ysh[tid] += h * inner;
      }
      __syncthreads();
    } // substeps
    if (g == 0 && tid < 96) {                    // out[iv+1] = Wl @ y + bl
      int c = tid >> 5, l = tid & 31;
      float acc = 0.f;
      for (int e = l; e < HID; e += 32) acc += Wl[c * HID + e] * ysh[e];
      for (int o = 16; o; o >>= 1) acc += __shfl_xor(acc, o);
      if (l == 0) out[(iv + 1) * 3 + c] = acc + bl[c];
    }
  }
}

extern "C" void kernel_launch(void* const* d_in, const int* in_sizes, int n_in,
                              void* d_out, int out_size, void* d_ws, size_t ws_size,
                              hipStream_t stream) {
  const float* ts  = (const float*)d_in[0];
  const float* cd  = (const float*)d_in[1];
  const float* cc  = (const float*)d_in[2];
  const float* cb  = (const float*)d_in[3];
  const float* ca  = (const float*)d_in[4];
  const float* Wi0 = (const float*)d_in[5];
  const float* bi0 = (const float*)d_in[6];
  const float* Wi1 = (const float*)d_in[7];
  const float* bi1 = (const float*)d_in[8];
  const float* Wi2 = (const float*)d_in[9];
  const float* bi2 = (const float*)d_in[10];
  const float* Wf0 = (const float*)d_in[11];
  const float* bf0 = (const float*)d_in[12];
  const float* Wf1 = (const float*)d_in[13];
  const float* bf1 = (const float*)d_in[14];
  const float* Wf2 = (const float*)d_in[15];
  const float* bf2 = (const float*)d_in[16];
  const float* Wl  = (const float*)d_in[17];
  const float* bl  = (const float*)d_in[18];
  float* out = (float*)d_out;
  float* wsf = (float*)d_ws;
  unsigned int* wsu = (unsigned int*)d_ws;

  hipLaunchKernelGGL(cde_init, dim3(1), dim3(1024), 0, stream, wsu);
  hipLaunchKernelGGL(cde_main, dim3(NWG), dim3(NT), 0, stream,
                     ts, cd, cc, cb, ca,
                     Wi0, bi0, Wi1, bi1, Wi2, bi2,
                     Wf0, bf0, Wf1, bf1, Wf2, bf2,
                     Wl, bl, out, wsf, wsu);
}

// Round 2
// 264138.403 us; speedup vs baseline: 1.3587x; 1.3587x over previous
//
#include <hip/hip_runtime.h>
#include <math.h>

// NeuralCDE on MI355X: sequential Tsit5 chain (2047*4 steps, 6 vf evals each).
// Weight-stationary across 32 persistent WGs. Layer-1 (Wf0) held per-thread in
// VGPRs and computed redundantly per WG -> ONE LLC flag-barrier per vf eval.
// All cross-WG traffic via RELAXED agent atomics (no buffer_inv/wbl2);
// data-before-flag ordering via __syncthreads' vmcnt(0) drain.

#define T_SAVE 2048
#define NCTRL 8
#define HID 128
#define WID 512
#define IN_DIM 136            // HID + NCTRL
#define NSUB 4
#define NWG 32
#define NT 512
#define RW 16                 // WID / NWG rows per WG (layer 2)
#define LC 16                 // WID / NWG cols per WG (layer 3 column split)
#define NQ 34                 // IN_DIM / 4

// ---- Tsit5 tableau (fp32, same literals as reference) ----
__device__ const float d_C[6] = {0.0f, 0.161f, 0.327f, 0.9f, 0.9800255409045097f, 1.0f};
__device__ const float d_AT[5][5] = {
  {0.161f, 0.f, 0.f, 0.f, 0.f},
  {-0.008480655492356989f, 0.335480655492357f, 0.f, 0.f, 0.f},
  {2.8971530571054935f, -6.359448489975075f, 4.3622954328695815f, 0.f, 0.f},
  {5.325864828439257f, -11.748883564062828f, 7.4955393428898365f, -0.09249506636175525f, 0.f},
  {5.86145544294642f, -12.92096931784711f, 8.159367898576159f, -0.071584973281401f, -0.028269050394068383f}
};
__device__ const float d_BT[6] = {0.09646076681806523f, 0.01f, 0.4798896504144996f,
                                  1.379008574103742f, -3.290069515436081f, 2.324710524099774f};

__device__ __forceinline__ float softplus_f(float x) {
  return fmaxf(x, 0.0f) + log1pf(expf(-fabsf(x)));
}

// Relaxed agent-scope (LLC-coherent, NO cache-maintenance ops emitted).
__device__ __forceinline__ void g_storef(float* p, float v) {
  __hip_atomic_store(p, v, __ATOMIC_RELAXED, __HIP_MEMORY_SCOPE_AGENT);
}
__device__ __forceinline__ float g_loadf(float* p) {
  return __hip_atomic_load(p, __ATOMIC_RELAXED, __HIP_MEMORY_SCOPE_AGENT);
}
__device__ __forceinline__ void g_storeu(unsigned int* p, unsigned int v) {
  __hip_atomic_store(p, v, __ATOMIC_RELAXED, __HIP_MEMORY_SCOPE_AGENT);
}
__device__ __forceinline__ unsigned int g_loadu(unsigned int* p) {
  return __hip_atomic_load(p, __ATOMIC_RELAXED, __HIP_MEMORY_SCOPE_AGENT);
}

// diffrax CubicInterpolation.evaluate: idx = clip(searchsorted(ts,t,'right')-1, 0, T-2)
__device__ __forceinline__ float ctrl_u(const float* __restrict__ ts,
                                        const float* __restrict__ ca, const float* __restrict__ cb,
                                        const float* __restrict__ cc, const float* __restrict__ cd,
                                        float t, int hint, int ch) {
  int idx = hint;
  while (idx + 1 <= T_SAVE - 1 && ts[idx + 1] <= t) ++idx;
  while (idx > 0 && ts[idx] > t) --idx;
  if (idx > T_SAVE - 2) idx = T_SAVE - 2;
  float x = t - ts[idx];
  int o = idx * NCTRL + ch;
  return ca[o] + x * (cb[o] + x * (cc[o] + x * cd[o]));
}

extern "C" __global__ void cde_init(unsigned int* wsu) {
  int i = threadIdx.x;
  if (i < NWG * 32) wsu[i] = 0;
}

extern "C" __global__ void __launch_bounds__(NT, 2)
cde_main(const float* __restrict__ ts,
         const float* __restrict__ cd, const float* __restrict__ cc,
         const float* __restrict__ cb, const float* __restrict__ ca,
         const float* __restrict__ Wi0, const float* __restrict__ bi0,
         const float* __restrict__ Wi1, const float* __restrict__ bi1,
         const float* __restrict__ Wi2, const float* __restrict__ bi2,
         const float* __restrict__ Wf0, const float* __restrict__ bf0,
         const float* __restrict__ Wf1, const float* __restrict__ bf1,
         const float* __restrict__ Wf2, const float* __restrict__ bf2,
         const float* __restrict__ Wl,  const float* __restrict__ bl,
         float* __restrict__ out, float* __restrict__ wsf, unsigned int* __restrict__ wsu)
{
  const int g = blockIdx.x;
  const int tid = threadIdx.x;

  unsigned int* slots = wsu;            // [NWG*32] epoch slots (4 KB)
  float* pkbuf = wsf + 1024;            // [2][NWG][HID] ping-pong partial-k

  __shared__ __align__(16) float w1s[RW * WID];      // Wf1 row slice (32 KB)
  __shared__ __align__(16) float w2s[LC * HID];      // Wf2 col slice [lc][i] (8 KB)
  __shared__ float bf1s[RW], bf2s[HID];
  __shared__ __align__(16) float xv[IN_DIM];
  __shared__ __align__(16) float h1s[WID];
  __shared__ float h2s[RW];
  __shared__ float ks[6][HID];
  __shared__ float ysh[HID];
  __shared__ __align__(16) float psum[4 * HID];
  __shared__ float uc[6][NCTRL];
  __shared__ int s_dead;

  unsigned int ep = 0;
  const int r0 = g * RW;
  if (tid == 0) s_dead = 0;

  // ---- per-thread Wf0 row (tid) into VGPRs; bias in a register ----
  float4 w0q[NQ];
  #pragma unroll
  for (int q = 0; q < NQ; ++q)
    w0q[q] = *(const float4*)&Wf0[(size_t)tid * IN_DIM + 4 * q];
  const float bf0r = bf0[tid];

  // ---- WG-local weight slices into LDS ----
  for (int i = tid; i < RW * WID; i += NT) {
    int r = i >> 9, c = i & (WID - 1);
    w1s[i] = Wf1[(r0 + r) * WID + c];
  }
  for (int i = tid; i < LC * HID; i += NT) {
    int lc = i >> 7, row = i & (HID - 1);
    w2s[i] = Wf2[row * WID + (g * LC + lc)];
  }
  if (tid < RW) bf1s[tid] = bf1[r0 + tid];
  if (tid < HID) bf2s[tid] = bf2[tid];

  // ---- init MLP, fully redundant per WG (no cross-WG sync) ----
  if (tid < NCTRL) xv[HID + tid] = ctrl_u(ts, ca, cb, cc, cd, ts[0], 0, tid);
  __syncthreads();
  {
    float acc = bi0[tid];
    #pragma unroll
    for (int e = 0; e < NCTRL; ++e) acc += Wi0[tid * NCTRL + e] * xv[HID + e];
    h1s[tid] = fmaxf(acc, 0.f);
  }
  __syncthreads();
  {
    int w = tid >> 6, l = tid & 63;
    for (int p = 0; p < 64; ++p) {
      int row = (w << 6) + p;
      float acc = 0.f;
      #pragma unroll
      for (int m = 0; m < 8; ++m) { int e = l + (m << 6); acc += Wi1[(size_t)row * WID + e] * h1s[e]; }
      #pragma unroll
      for (int o = 32; o; o >>= 1) acc += __shfl_xor(acc, o);
      if (l == 0) psum[row] = fmaxf(acc + bi1[row], 0.f);
    }
  }
  __syncthreads();
  {
    int w = tid >> 6, l = tid & 63;
    for (int p = 0; p < 16; ++p) {
      int row = (w << 4) + p;
      float acc = 0.f;
      #pragma unroll
      for (int m = 0; m < 8; ++m) { int e = l + (m << 6); acc += Wi2[(size_t)row * WID + e] * psum[e]; }
      #pragma unroll
      for (int o = 32; o; o >>= 1) acc += __shfl_xor(acc, o);
      if (l == 0) ysh[row] = acc + bi2[row];
    }
  }
  __syncthreads();
  if (g == 0 && tid < 96) {                      // out[0] = Wl @ y0 + bl
    int c = tid >> 5, l = tid & 31;
    float acc = 0.f;
    for (int e = l; e < HID; e += 32) acc += Wl[c * HID + e] * ysh[e];
    #pragma unroll
    for (int o = 16; o; o >>= 1) acc += __shfl_xor(acc, o);
    if (l == 0) out[c] = acc + bl[c];
  }

  // ---- main sequential time loop ----
  for (int iv = 0; iv < T_SAVE - 1; ++iv) {
    float t0 = ts[iv], t1 = ts[iv + 1];
    float h = (t1 - t0) * 0.25f;
    for (int j = 0; j < NSUB; ++j) {
      float tj = t0 + (float)j * h;
      // hoist all 6 stage-time control evals off the critical path
      if (tid >= 128 && tid < 176) {
        int st = (tid - 128) >> 3, ch = (tid - 128) & 7;
        uc[st][ch] = ctrl_u(ts, ca, cb, cc, cd, tj + d_C[st] * h, iv, ch);
      }
      for (int s = 0; s < 6; ++s) {
        // build x = [y_stage ; u(t_stage)]
        if (tid < HID) {
          float v = ysh[tid];
          if (s > 0) {
            float inner = 0.f;
            for (int m = 0; m < s; ++m) inner += d_AT[s - 1][m] * ks[m][tid];
            v += h * inner;
          }
          xv[tid] = v;
        } else if (tid < IN_DIM) {
          xv[tid] = uc[s][tid - HID];
        }
        __syncthreads();
        // L1, redundant full width: thread t owns row t (weights in VGPRs)
        {
          float acc = 0.f;
          #pragma unroll
          for (int q = 0; q < NQ; ++q) {
            float4 x4 = *(const float4*)&xv[4 * q];
            float4 w4 = w0q[q];
            acc += w4.x * x4.x + w4.y * x4.y + w4.z * x4.z + w4.w * x4.w;
          }
          h1s[tid] = softplus_f(acc + bf0r);
        }
        __syncthreads();
        // L2 slice: 16 local rows, 2 per wave
        {
          int w = tid >> 6, l = tid & 63;
          int ra = w * 2;
          float acc0 = 0.f, acc1 = 0.f;
          #pragma unroll
          for (int m = 0; m < 2; ++m) {
            int c0 = 4 * l + 256 * m;
            float4 xq = *(const float4*)&h1s[c0];
            float4 wa = *(const float4*)&w1s[ra * WID + c0];
            float4 wb = *(const float4*)&w1s[(ra + 1) * WID + c0];
            acc0 += wa.x*xq.x + wa.y*xq.y + wa.z*xq.z + wa.w*xq.w;
            acc1 += wb.x*xq.x + wb.y*xq.y + wb.z*xq.z + wb.w*xq.w;
          }
          #pragma unroll
          for (int o = 32; o; o >>= 1) { acc0 += __shfl_xor(acc0, o); acc1 += __shfl_xor(acc1, o); }
          if (l == 0) {
            h2s[ra]     = softplus_f(acc0 + bf1s[ra]);
            h2s[ra + 1] = softplus_f(acc1 + bf1s[ra + 1]);
          }
        }
        __syncthreads();
        // L3 partial-k from Wf2 column slice
        {
          int i = tid & (HID - 1), q = tid >> 7;
          float acc = 0.f;
          #pragma unroll
          for (int n = 0; n < 4; ++n) acc += w2s[(q * 4 + n) * HID + i] * h2s[q * 4 + n];
          psum[q * HID + i] = acc;
        }
        __syncthreads();
        // single barrier per vf: post partial-k (ping-pong by epoch parity)
        ++ep;
        float* pk = pkbuf + (ep & 1) * (NWG * HID);
        if (tid < HID) {
          float tot = psum[tid] + psum[HID + tid] + psum[2 * HID + tid] + psum[3 * HID + tid];
          g_storef(&pk[g * HID + tid], tot);
        }
        __syncthreads();   // drains vmcnt(0): partial-k complete at LLC before flag
        if (tid == 0) g_storeu(&slots[g * 32], ep);
        if (((tid & 63) < 32) && !s_dead) {
          int sl = (tid & 31) * 32;
          unsigned int guard = 0;
          while (g_loadu(&slots[sl]) < ep) {
            if (++guard > (1u << 14)) { s_dead = 1; break; }
          }
        }
        asm volatile("" ::: "memory");
        // deterministic redundant sum of 32 partials -> k_s
        {
          int i = tid & (HID - 1), q = tid >> 7;
          float acc = 0.f;
          #pragma unroll
          for (int m = 0; m < 8; ++m) acc += g_loadf(&pk[(q * 8 + m) * HID + i]);
          psum[q * HID + i] = acc;
        }
        __syncthreads();
        if (tid < HID) {
          float tot = psum[tid] + psum[HID + tid] + psum[2 * HID + tid] + psum[3 * HID + tid];
          ks[s][tid] = tanhf(tot + bf2s[tid]);
        }
        __syncthreads();
      } // stages
      if (tid < HID) {
        float inner = 0.f;
        #pragma unroll
        for (int m = 0; m < 6; ++m) inner += d_BT[m] * ks[m][tid];
        ysh[tid] += h * inner;
      }
      __syncthreads();
    } // substeps
    if (g == 0 && tid < 96) {                    // out[iv+1] = Wl @ y + bl
      int c = tid >> 5, l = tid & 31;
      float acc = 0.f;
      for (int e = l; e < HID; e += 32) acc += Wl[c * HID + e] * ysh[e];
      #pragma unroll
      for (int o = 16; o; o >>= 1) acc += __shfl_xor(acc, o);
      if (l == 0) out[(iv + 1) * 3 + c] = acc + bl[c];
    }
  }
}

extern "C" void kernel_launch(void* const* d_in, const int* in_sizes, int n_in,
                              void* d_out, int out_size, void* d_ws, size_t ws_size,
                              hipStream_t stream) {
  const float* ts  = (const float*)d_in[0];
  const float* cd  = (const float*)d_in[1];
  const float* cc  = (const float*)d_in[2];
  const float* cb  = (const float*)d_in[3];
  const float* ca  = (const float*)d_in[4];
  const float* Wi0 = (const float*)d_in[5];
  const float* bi0 = (const float*)d_in[6];
  const float* Wi1 = (const float*)d_in[7];
  const float* bi1 = (const float*)d_in[8];
  const float* Wi2 = (const float*)d_in[9];
  const float* bi2 = (const float*)d_in[10];
  const float* Wf0 = (const float*)d_in[11];
  const float* bf0 = (const float*)d_in[12];
  const float* Wf1 = (const float*)d_in[13];
  const float* bf1 = (const float*)d_in[14];
  const float* Wf2 = (const float*)d_in[15];
  const float* bf2 = (const float*)d_in[16];
  const float* Wl  = (const float*)d_in[17];
  const float* bl  = (const float*)d_in[18];
  float* out = (float*)d_out;
  float* wsf = (float*)d_ws;
  unsigned int* wsu = (unsigned int*)d_ws;

  hipLaunchKernelGGL(cde_init, dim3(1), dim3(1024), 0, stream, wsu);
  hipLaunchKernelGGL(cde_main, dim3(NWG), dim3(NT), 0, stream,
                     ts, cd, cc, cb, ca,
                     Wi0, bi0, Wi1, bi1, Wi2, bi2,
                     Wf0, bf0, Wf1, bf1, Wf2, bf2,
                     Wl, bl, out, wsf, wsu);
}